// Round 9
// baseline (478.107 us; speedup 1.0000x reference)
//
#include <hip/hip_runtime.h>
#include <cstdint>
#include <cstddef>

#define DIM 16384
#define BSIZE 32
#define MAX_STEPS 9
#define TPB1 256
#define TPB3 1024
#define KV 4  // float4 vectors per thread in K3 (4*4*1024 = 16384)

typedef float f32x4 __attribute__((ext_vector_type(4)));

__device__ __forceinline__ float rdlane(float v, int l) {
    return __int_as_float(__builtin_amdgcn_readlane(__float_as_int(v), l));
}

// ---------------- P: pure-read probe of K1's exact W access pattern ----------------
// grid (16, 32), 256 thr; f32x4 per thread, rows strided by DIM, 16-row load
// batches (16KB/wave in flight). Measures the DRAM ceiling for this pattern.
__global__ __launch_bounds__(256) void k_probe(const float* __restrict__ W,
                                               float* __restrict__ dummy) {
    const int t = threadIdx.x;
    const int c0 = (blockIdx.x * 256 + t) * 4;
    const size_t j0 = (size_t)blockIdx.y * 512;
    const float* wp = W + j0 * DIM + c0;
    f32x4 acc0 = (f32x4)(0.f), acc1 = (f32x4)(0.f);
    for (int g = 0; g < 512; g += 16) {
        f32x4 v[16];
#pragma unroll
        for (int r = 0; r < 16; ++r)
            v[r] = *(const f32x4*)(wp + (size_t)(g + r) * DIM);
#pragma unroll
        for (int r = 0; r < 16; r += 2) { acc0 += v[r]; acc1 += v[r + 1]; }
    }
    f32x4 s = acc0 + acc1;
    *(f32x4*)(dummy + (((size_t)blockIdx.y * 16 + blockIdx.x) * 256 + t) * 4) = s;
}

// ---------------- K0: tiled transpose x [B][D] -> xT [D][B] ----------------
__global__ __launch_bounds__(256) void k_xpose(const float* __restrict__ x,
                                               float* __restrict__ xT) {
    __shared__ float tile[64][33];
    const int j0 = blockIdx.x * 64;
    const int t = threadIdx.x;
    {
        int col = t & 63;
        int r0 = t >> 6;  // 0..3
#pragma unroll
        for (int r = 0; r < 8; ++r) {
            int row = r * 4 + r0;  // 0..31
            tile[col][row] = x[(size_t)row * DIM + j0 + col];
        }
    }
    __syncthreads();
    {
        int b = t & 31;
        int q0 = t >> 5;  // 0..7
#pragma unroll
        for (int r = 0; r < 8; ++r) {
            int jj = r * 8 + q0;  // 0..63
            xT[(size_t)(j0 + jj) * BSIZE + b] = tile[jj][b];
        }
    }
}

// ------- K1 (R3 structure, best known): readlane x-broadcast, 3-deep W prefetch -------
__global__ __launch_bounds__(TPB1, 2) void k_matmul(
        const float* __restrict__ W, const float* __restrict__ xT,
        float* __restrict__ partial, int jb) {
    const int t = threadIdx.x;
    const int l6 = t & 63;                       // lane within wave
    const int c0 = (blockIdx.x * TPB1 + t) * 4;  // 4 columns per thread
    const int j0 = blockIdx.y * jb;
    const int nch = jb >> 3;                     // 8 j's per chunk

    f32x4 acc[BSIZE];
#pragma unroll
    for (int b = 0; b < BSIZE; ++b) acc[b] = (f32x4)(0.f);

    // per-wave x chunk: lane l holds xT[j0*32 + ch*256 + 4l .. +3]
    const float* xbase = xT + (size_t)j0 * BSIZE + (size_t)l6 * 4;
    f32x4 xv = *(const f32x4*)xbase;

    f32x4 wv[11];
#pragma unroll
    for (int p = 0; p < 3; ++p)  // preload rows j0+0..2
        wv[p] = *(const f32x4*)(W + (size_t)(j0 + p) * DIM + c0);

    for (int ch = 0; ch < nch; ++ch) {
        int chn = (ch + 1 < nch) ? (ch + 1) : ch;
        f32x4 xnxt = *(const f32x4*)(xbase + (size_t)chn * 256);
#pragma unroll
        for (int jj = 0; jj < 8; ++jj) {
            int grow = j0 + ch * 8 + jj + 3;
            grow = (grow > DIM - 1) ? (DIM - 1) : grow;
            wv[jj + 3] = *(const f32x4*)(W + (size_t)grow * DIM + c0);
            f32x4 w = wv[jj];
#pragma unroll
            for (int b4 = 0; b4 < 8; ++b4) {
                int ln = jj * 8 + b4;  // compile-time lane index
                float s0 = rdlane(xv.x, ln);
                float s1 = rdlane(xv.y, ln);
                float s2 = rdlane(xv.z, ln);
                float s3 = rdlane(xv.w, ln);
                acc[b4 * 4 + 0].x = fmaf(w.x, s0, acc[b4 * 4 + 0].x);
                acc[b4 * 4 + 0].y = fmaf(w.y, s0, acc[b4 * 4 + 0].y);
                acc[b4 * 4 + 0].z = fmaf(w.z, s0, acc[b4 * 4 + 0].z);
                acc[b4 * 4 + 0].w = fmaf(w.w, s0, acc[b4 * 4 + 0].w);
                acc[b4 * 4 + 1].x = fmaf(w.x, s1, acc[b4 * 4 + 1].x);
                acc[b4 * 4 + 1].y = fmaf(w.y, s1, acc[b4 * 4 + 1].y);
                acc[b4 * 4 + 1].z = fmaf(w.z, s1, acc[b4 * 4 + 1].z);
                acc[b4 * 4 + 1].w = fmaf(w.w, s1, acc[b4 * 4 + 1].w);
                acc[b4 * 4 + 2].x = fmaf(w.x, s2, acc[b4 * 4 + 2].x);
                acc[b4 * 4 + 2].y = fmaf(w.y, s2, acc[b4 * 4 + 2].y);
                acc[b4 * 4 + 2].z = fmaf(w.z, s2, acc[b4 * 4 + 2].z);
                acc[b4 * 4 + 2].w = fmaf(w.w, s2, acc[b4 * 4 + 2].w);
                acc[b4 * 4 + 3].x = fmaf(w.x, s3, acc[b4 * 4 + 3].x);
                acc[b4 * 4 + 3].y = fmaf(w.y, s3, acc[b4 * 4 + 3].y);
                acc[b4 * 4 + 3].z = fmaf(w.z, s3, acc[b4 * 4 + 3].z);
                acc[b4 * 4 + 3].w = fmaf(w.w, s3, acc[b4 * 4 + 3].w);
            }
        }
        wv[0] = wv[8]; wv[1] = wv[9]; wv[2] = wv[10];
        xv = xnxt;
    }

    f32x4* pp = (f32x4*)(partial + (size_t)blockIdx.y * BSIZE * DIM);
    const int c4 = c0 >> 2;
#pragma unroll
    for (int b = 0; b < BSIZE; ++b) pp[(size_t)b * (DIM / 4) + c4] = acc[b];
}

// ------- K2: h0 = sum_slots partial + bias (float4, deterministic order) -------
__global__ __launch_bounds__(256) void k_reduce(const float* __restrict__ partial,
                                                const float* __restrict__ bias,
                                                float* __restrict__ h0, int nslots) {
    int i4 = blockIdx.x * 256 + threadIdx.x;  // over B*DIM/4
    int c4 = i4 & (DIM / 4 - 1);
    const f32x4* p = (const f32x4*)partial;
    f32x4 s = ((const f32x4*)bias)[c4];
    for (int sl = 0; sl < nslots; ++sl)
        s += p[(size_t)sl * (BSIZE * DIM / 4) + i4];
    ((f32x4*)h0)[i4] = s;
}

// ---------------- K3 block-wide reductions (1024 thr = 16 waves) ----------------
__device__ __forceinline__ float block_reduce_max(float v, float* red) {
#pragma unroll
    for (int off = 1; off < 64; off <<= 1) v = fmaxf(v, __shfl_xor(v, off));
    int lane = threadIdx.x & 63, wv = threadIdx.x >> 6;
    if (lane == 0) red[wv] = v;
    __syncthreads();
    float m = red[0];
#pragma unroll
    for (int w = 1; w < TPB3 / 64; ++w) m = fmaxf(m, red[w]);
    __syncthreads();  // allow red[] reuse
    return m;
}

__device__ __forceinline__ float block_reduce_sum(float v, float* red) {
#pragma unroll
    for (int off = 1; off < 64; off <<= 1) v += __shfl_xor(v, off);
    int lane = threadIdx.x & 63, wv = threadIdx.x >> 6;
    if (lane == 0) red[wv] = v;
    __syncthreads();
    float s = red[0];
#pragma unroll
    for (int w = 1; w < TPB3 / 64; ++w) s += red[w];
    __syncthreads();
    return s;
}

// ------- K3: per-row sampler, one block per batch row, h/sg in registers -------
__global__ __launch_bounds__(TPB3) void k_sample(
        const float* __restrict__ x, const float* __restrict__ W,
        const float* __restrict__ h0, const float* __restrict__ gumbel,
        const float* __restrict__ au, const int* __restrict__ radius,
        float* __restrict__ out) {
    __shared__ float redf[TPB3 / 64];
    __shared__ int   redi[TPB3 / 64];
    __shared__ float s_delta;
    const int b = blockIdx.x;
    const int t = threadIdx.x;
    const int lane = t & 63, wvi = t >> 6;

    const f32x4* h0v = (const f32x4*)(h0 + (size_t)b * DIM);
    const f32x4* xin = (const f32x4*)(x + (size_t)b * DIM);

    f32x4 h[4], sg[4];
#pragma unroll
    for (int v = 0; v < 4; ++v) {
        h[v] = h0v[t + v * TPB3];
        f32x4 xx = xin[t + v * TPB3];
        sg[v] = (f32x4)(1.0f) - 2.0f * xx;  // exactly +/-1
    }

    // Zx = logsumexp(sg*h*0.5)
    float lmax = -INFINITY;
#pragma unroll
    for (int v = 0; v < 4; ++v) {
        f32x4 l = sg[v] * h[v] * 0.5f;
        lmax = fmaxf(lmax, fmaxf(fmaxf(l.x, l.y), fmaxf(l.z, l.w)));
    }
    float m = block_reduce_max(lmax, redf);
    float lsum = 0.f;
#pragma unroll
    for (int v = 0; v < 4; ++v) {
        f32x4 l = sg[v] * h[v] * 0.5f;
        lsum += expf(l.x - m) + expf(l.y - m) + expf(l.z - m) + expf(l.w - m);
    }
    float S = block_reduce_sum(lsum, redf);
    float Zx = logf(S) + m;

    int rad = radius[b];
    rad = rad < 0 ? 0 : (rad > MAX_STEPS ? MAX_STEPS : rad);

    f32x4 gc[4];
    {
        const f32x4* gp = (const f32x4*)(gumbel + (size_t)b * DIM);  // step 0 row
#pragma unroll
        for (int v = 0; v < 4; ++v) gc[v] = gp[t + v * TPB3];
    }

    for (int st = 0; st < rad; ++st) {
        // scores + thread-local argmax (ascending index; strict > keeps first max)
        float best = -INFINITY; int bidx = 0;
#pragma unroll
        for (int v = 0; v < 4; ++v) {
            f32x4 l = sg[v] * h[v] * 0.5f + gc[v];
            int base = (t + v * TPB3) * 4;
            if (l.x > best) { best = l.x; bidx = base; }
            if (l.y > best) { best = l.y; bidx = base + 1; }
            if (l.z > best) { best = l.z; bidx = base + 2; }
            if (l.w > best) { best = l.w; bidx = base + 3; }
        }
        // wave reduce (min-idx tie-break)
#pragma unroll
        for (int off = 1; off < 64; off <<= 1) {
            float ov = __shfl_xor(best, off);
            int oi = __shfl_xor(bidx, off);
            if (ov > best || (ov == best && oi < bidx)) { best = ov; bidx = oi; }
        }
        if (lane == 0) { redf[wvi] = best; redi[wvi] = bidx; }
        // prefetch next gumbel row; overlaps both barriers
        if (st + 1 < rad) {
            const f32x4* gp = (const f32x4*)(gumbel + ((size_t)(st + 1) * BSIZE + b) * DIM);
#pragma unroll
            for (int v = 0; v < 4; ++v) gc[v] = gp[t + v * TPB3];
        }
        __syncthreads();  // bar1: leader entries visible
        // all threads scan the 16 leader entries (identical result)
        float bv = redf[0]; int bi = redi[0];
#pragma unroll
        for (int w = 1; w < TPB3 / 64; ++w) {
            float ov = redf[w]; int oi = redi[w];
            if (ov > bv || (ov == bv && oi < bi)) { bv = ov; bi = oi; }
        }
        const int idx = bi;
        // issue W-row loads now; latency overlaps bar2
        const f32x4* wr4 = (const f32x4*)(W + (size_t)idx * DIM);
        f32x4 wl0 = wr4[t];
        f32x4 wl1 = wr4[t + TPB3];
        f32x4 wl2 = wr4[t + 2 * TPB3];
        f32x4 wl3 = wr4[t + 3 * TPB3];
        // owner flips its sign and publishes delta = (1 - 2*x_old)
        int c4 = idx >> 2, towner = c4 & (TPB3 - 1), vsel = c4 >> 10, e = idx & 3;
        if (t == towner) {
            f32x4 s4;
            if (vsel == 0) s4 = sg[0]; else if (vsel == 1) s4 = sg[1];
            else if (vsel == 2) s4 = sg[2]; else s4 = sg[3];
            float d = (e == 0) ? s4.x : (e == 1) ? s4.y : (e == 2) ? s4.z : s4.w;
            if (e == 0) s4.x = -s4.x; else if (e == 1) s4.y = -s4.y;
            else if (e == 2) s4.z = -s4.z; else s4.w = -s4.w;
            if (vsel == 0) sg[0] = s4; else if (vsel == 1) sg[1] = s4;
            else if (vsel == 2) sg[2] = s4; else sg[3] = s4;
            s_delta = d;
        }
        __syncthreads();  // bar2: s_delta visible; also protects redf/redi reuse
        float delta = s_delta;
        h[0].x = fmaf(delta, wl0.x, h[0].x); h[0].y = fmaf(delta, wl0.y, h[0].y);
        h[0].z = fmaf(delta, wl0.z, h[0].z); h[0].w = fmaf(delta, wl0.w, h[0].w);
        h[1].x = fmaf(delta, wl1.x, h[1].x); h[1].y = fmaf(delta, wl1.y, h[1].y);
        h[1].z = fmaf(delta, wl1.z, h[1].z); h[1].w = fmaf(delta, wl1.w, h[1].w);
        h[2].x = fmaf(delta, wl2.x, h[2].x); h[2].y = fmaf(delta, wl2.y, h[2].y);
        h[2].z = fmaf(delta, wl2.z, h[2].z); h[2].w = fmaf(delta, wl2.w, h[2].w);
        h[3].x = fmaf(delta, wl3.x, h[3].x); h[3].y = fmaf(delta, wl3.y, h[3].y);
        h[3].z = fmaf(delta, wl3.z, h[3].z); h[3].w = fmaf(delta, wl3.w, h[3].w);
    }

    // Zy
    lmax = -INFINITY;
#pragma unroll
    for (int v = 0; v < 4; ++v) {
        f32x4 l = sg[v] * h[v] * 0.5f;
        lmax = fmaxf(lmax, fmaxf(fmaxf(l.x, l.y), fmaxf(l.z, l.w)));
    }
    m = block_reduce_max(lmax, redf);
    lsum = 0.f;
#pragma unroll
    for (int v = 0; v < 4; ++v) {
        f32x4 l = sg[v] * h[v] * 0.5f;
        lsum += expf(l.x - m) + expf(l.y - m) + expf(l.z - m) + expf(l.w - m);
    }
    S = block_reduce_sum(lsum, redf);
    float Zy = logf(S) + m;

    int accepted = (expf(Zx - Zy) >= au[b]) ? 1 : 0;
    f32x4* ov = (f32x4*)(out + (size_t)b * DIM);
#pragma unroll
    for (int v = 0; v < 4; ++v) {
        f32x4 y;
        y.x = (sg[v].x < 0.f) ? 1.f : 0.f;
        y.y = (sg[v].y < 0.f) ? 1.f : 0.f;
        y.z = (sg[v].z < 0.f) ? 1.f : 0.f;
        y.w = (sg[v].w < 0.f) ? 1.f : 0.f;
        ov[t + v * TPB3] = accepted ? y : xin[t + v * TPB3];
    }
}

extern "C" void kernel_launch(void* const* d_in, const int* in_sizes, int n_in,
                              void* d_out, int out_size, void* d_ws, size_t ws_size,
                              hipStream_t stream) {
    (void)in_sizes; (void)n_in; (void)out_size;
    const float* x      = (const float*)d_in[0];
    const float* W      = (const float*)d_in[1];
    const float* bias   = (const float*)d_in[2];
    const float* gumbel = (const float*)d_in[3];
    const float* au     = (const float*)d_in[4];
    const int*   radius = (const int*)d_in[5];
    float* out = (float*)d_out;

    // ws layout: xT (2 MB) | partial (nslots * 2 MB) | h0 (2 MB) | dummy (2 MB)
    float* xT = (float*)d_ws;
    size_t xt_elems = (size_t)DIM * BSIZE;
    int nslots = 32;
    while (nslots > 1) {
        size_t need = (xt_elems + (size_t)(nslots + 2) * BSIZE * DIM) * sizeof(float);
        if (need <= ws_size) break;
        nslots >>= 1;
    }
    float* partial = xT + xt_elems;
    float* h0 = partial + (size_t)nslots * BSIZE * DIM;
    float* dummy = h0 + (size_t)BSIZE * DIM;

    // DIAGNOSTIC: pure-read probe of K1's W access pattern (adds its time to dur_us)
    k_probe<<<dim3(16, 32), 256, 0, stream>>>(W, dummy);

    k_xpose<<<DIM / 64, 256, 0, stream>>>(x, xT);
    dim3 g1(DIM / (TPB1 * 4), nslots);
    k_matmul<<<g1, TPB1, 0, stream>>>(W, xT, partial, DIM / nslots);
    k_reduce<<<(BSIZE * DIM / 4) / 256, 256, 0, stream>>>(partial, bias, h0, nslots);
    k_sample<<<BSIZE, TPB3, 0, stream>>>(x, W, h0, gumbel, au, radius, out);
}

// Round 10
// 299.535 us; speedup vs baseline: 1.5962x; 1.5962x over previous
//
#include <hip/hip_runtime.h>
#include <cstdint>
#include <cstddef>

#define DIM 16384
#define BSIZE 32
#define MAX_STEPS 9
#define TPB1 256
#define TPB3 1024
#define JB 512
#define NSLOTS (DIM / JB)  // 32
#define BATCH 16

typedef float f32x4 __attribute__((ext_vector_type(4)));

__device__ __forceinline__ float rdlane(float v, int l) {
    return __int_as_float(__builtin_amdgcn_readlane(__float_as_int(v), l));
}

// ---------------- K0: tiled transpose x [B][D] -> xT [D][B] ----------------
__global__ __launch_bounds__(256) void k_xpose(const float* __restrict__ x,
                                               float* __restrict__ xT) {
    __shared__ float tile[64][33];
    const int j0 = blockIdx.x * 64;
    const int t = threadIdx.x;
    {
        int col = t & 63;
        int r0 = t >> 6;  // 0..3
#pragma unroll
        for (int r = 0; r < 8; ++r) {
            int row = r * 4 + r0;  // 0..31
            tile[col][row] = x[(size_t)row * DIM + j0 + col];
        }
    }
    __syncthreads();
    {
        int b = t & 31;
        int q0 = t >> 5;  // 0..7
#pragma unroll
        for (int r = 0; r < 8; ++r) {
            int jj = r * 8 + q0;  // 0..63
            xT[(size_t)(j0 + jj) * BSIZE + b] = tile[jj][b];
        }
    }
}

// ------- K1: probe-mirror matmul. partial[slot][b][c] = sum_j x[b][j]*W[j][c] -------
// Load shape cloned from the 6.4 TB/s probe: 16 W rows (f32x4/lane) issued
// back-to-back per batch, consumed with compiler fine-grained vmcnt. x for the
// 16 rows (512 floats) rides ahead of the W batch as 2 f32x4/lane; values are
// extracted with compile-time v_readlane and feed v_pk_fma_f32 (2 per batch
// element). Per row: 32 rdlane + 64 pk_fma = 96 VALU instr (~48% issue at full
// HBM pace). grid (16, 32) = 512 blocks = 2/CU = 8 waves/CU (same as probe).
__global__ __launch_bounds__(TPB1, 2) void k_matmul(
        const float* __restrict__ W, const float* __restrict__ xT,
        float* __restrict__ partial) {
    const int t = threadIdx.x;
    const int l = t & 63;
    const int c0 = (blockIdx.x * TPB1 + t) * 4;
    const int j0 = blockIdx.y * JB;

    f32x4 acc[BSIZE];
#pragma unroll
    for (int b = 0; b < BSIZE; ++b) acc[b] = (f32x4)(0.f);

    const float* wp = W + (size_t)j0 * DIM + c0;
    const float* xp = xT + (size_t)j0 * BSIZE;

    for (int g = 0; g < JB / BATCH; ++g) {  // 32 batches
        // x for rows g*16..g*16+15: 512 floats; lane l holds 8 (2 x f32x4).
        // issued BEFORE the W batch so waiting on x never drains the W stream.
        f32x4 xv0 = *(const f32x4*)(xp + (size_t)g * 512 + l * 4);
        f32x4 xv1 = *(const f32x4*)(xp + (size_t)g * 512 + 256 + l * 4);
        // W batch: 16 rows issued back-to-back (probe shape)
        f32x4 v[BATCH];
#pragma unroll
        for (int r = 0; r < BATCH; ++r)
            v[r] = *(const f32x4*)(wp + (size_t)(g * BATCH + r) * DIM);
        // compute: row r batch b -> x float at flat (r*32+b) of the 512-block:
        // reg r>>3, lane (r&7)*8 + (b>>2), elem b&3  (all compile-time)
#pragma unroll
        for (int r = 0; r < BATCH; ++r) {
            f32x4 w4 = v[r];
#pragma unroll
            for (int b = 0; b < BSIZE; ++b) {
                float xs = (r < 8) ? rdlane(xv0[b & 3], (r & 7) * 8 + (b >> 2))
                                   : rdlane(xv1[b & 3], (r & 7) * 8 + (b >> 2));
                acc[b] = __builtin_elementwise_fma(w4, (f32x4)(xs), acc[b]);
            }
        }
    }

    float* pbase = partial + (size_t)blockIdx.y * BSIZE * DIM + c0;
#pragma unroll
    for (int b = 0; b < BSIZE; ++b)
        *(f32x4*)(pbase + (size_t)b * DIM) = acc[b];
}

// ------- K2: h0 = sum_slots partial + bias (float4, deterministic order) -------
__global__ __launch_bounds__(256) void k_reduce(const float* __restrict__ partial,
                                                const float* __restrict__ bias,
                                                float* __restrict__ h0) {
    int i4 = blockIdx.x * 256 + threadIdx.x;  // over B*DIM/4
    int c4 = i4 & (DIM / 4 - 1);
    const f32x4* p = (const f32x4*)partial;
    f32x4 s = ((const f32x4*)bias)[c4];
#pragma unroll 4
    for (int sl = 0; sl < NSLOTS; ++sl)
        s += p[(size_t)sl * (BSIZE * DIM / 4) + i4];
    ((f32x4*)h0)[i4] = s;
}

// ---------------- K3 block-wide reductions (1024 thr = 16 waves) ----------------
__device__ __forceinline__ float block_reduce_max(float v, float* red) {
#pragma unroll
    for (int off = 1; off < 64; off <<= 1) v = fmaxf(v, __shfl_xor(v, off));
    int lane = threadIdx.x & 63, wv = threadIdx.x >> 6;
    if (lane == 0) red[wv] = v;
    __syncthreads();
    float m = red[0];
#pragma unroll
    for (int w = 1; w < TPB3 / 64; ++w) m = fmaxf(m, red[w]);
    __syncthreads();  // allow red[] reuse
    return m;
}

__device__ __forceinline__ float block_reduce_sum(float v, float* red) {
#pragma unroll
    for (int off = 1; off < 64; off <<= 1) v += __shfl_xor(v, off);
    int lane = threadIdx.x & 63, wv = threadIdx.x >> 6;
    if (lane == 0) red[wv] = v;
    __syncthreads();
    float s = red[0];
#pragma unroll
    for (int w = 1; w < TPB3 / 64; ++w) s += red[w];
    __syncthreads();
    return s;
}

// ------- K3: per-row sampler, one block per batch row, h/sg in registers -------
__global__ __launch_bounds__(TPB3) void k_sample(
        const float* __restrict__ x, const float* __restrict__ W,
        const float* __restrict__ h0, const float* __restrict__ gumbel,
        const float* __restrict__ au, const int* __restrict__ radius,
        float* __restrict__ out) {
    __shared__ float redf[TPB3 / 64];
    __shared__ int   redi[TPB3 / 64];
    __shared__ float s_delta;
    const int b = blockIdx.x;
    const int t = threadIdx.x;
    const int lane = t & 63, wvi = t >> 6;

    const f32x4* h0v = (const f32x4*)(h0 + (size_t)b * DIM);
    const f32x4* xin = (const f32x4*)(x + (size_t)b * DIM);

    f32x4 h[4], sg[4];
#pragma unroll
    for (int v = 0; v < 4; ++v) {
        h[v] = h0v[t + v * TPB3];
        f32x4 xx = xin[t + v * TPB3];
        sg[v] = (f32x4)(1.0f) - 2.0f * xx;  // exactly +/-1
    }

    // Zx = logsumexp(sg*h*0.5)
    float lmax = -INFINITY;
#pragma unroll
    for (int v = 0; v < 4; ++v) {
        f32x4 l = sg[v] * h[v] * 0.5f;
        lmax = fmaxf(lmax, fmaxf(fmaxf(l.x, l.y), fmaxf(l.z, l.w)));
    }
    float m = block_reduce_max(lmax, redf);
    float lsum = 0.f;
#pragma unroll
    for (int v = 0; v < 4; ++v) {
        f32x4 l = sg[v] * h[v] * 0.5f;
        lsum += expf(l.x - m) + expf(l.y - m) + expf(l.z - m) + expf(l.w - m);
    }
    float S = block_reduce_sum(lsum, redf);
    float Zx = logf(S) + m;

    int rad = radius[b];
    rad = rad < 0 ? 0 : (rad > MAX_STEPS ? MAX_STEPS : rad);

    f32x4 gc[4];
    {
        const f32x4* gp = (const f32x4*)(gumbel + (size_t)b * DIM);  // step 0 row
#pragma unroll
        for (int v = 0; v < 4; ++v) gc[v] = gp[t + v * TPB3];
    }

    for (int st = 0; st < rad; ++st) {
        // scores + thread-local argmax (ascending index; strict > keeps first max)
        float best = -INFINITY; int bidx = 0;
#pragma unroll
        for (int v = 0; v < 4; ++v) {
            f32x4 l = sg[v] * h[v] * 0.5f + gc[v];
            int base = (t + v * TPB3) * 4;
            if (l.x > best) { best = l.x; bidx = base; }
            if (l.y > best) { best = l.y; bidx = base + 1; }
            if (l.z > best) { best = l.z; bidx = base + 2; }
            if (l.w > best) { best = l.w; bidx = base + 3; }
        }
        // wave reduce (min-idx tie-break)
#pragma unroll
        for (int off = 1; off < 64; off <<= 1) {
            float ov = __shfl_xor(best, off);
            int oi = __shfl_xor(bidx, off);
            if (ov > best || (ov == best && oi < bidx)) { best = ov; bidx = oi; }
        }
        if (lane == 0) { redf[wvi] = best; redi[wvi] = bidx; }
        // prefetch next gumbel row; overlaps both barriers
        if (st + 1 < rad) {
            const f32x4* gp = (const f32x4*)(gumbel + ((size_t)(st + 1) * BSIZE + b) * DIM);
#pragma unroll
            for (int v = 0; v < 4; ++v) gc[v] = gp[t + v * TPB3];
        }
        __syncthreads();  // bar1: leader entries visible
        // all threads scan the 16 leader entries (identical result)
        float bv = redf[0]; int bi = redi[0];
#pragma unroll
        for (int w = 1; w < TPB3 / 64; ++w) {
            float ov = redf[w]; int oi = redi[w];
            if (ov > bv || (ov == bv && oi < bi)) { bv = ov; bi = oi; }
        }
        const int idx = bi;
        // issue W-row loads now; latency overlaps bar2
        const f32x4* wr4 = (const f32x4*)(W + (size_t)idx * DIM);
        f32x4 wl0 = wr4[t];
        f32x4 wl1 = wr4[t + TPB3];
        f32x4 wl2 = wr4[t + 2 * TPB3];
        f32x4 wl3 = wr4[t + 3 * TPB3];
        // owner flips its sign and publishes delta = (1 - 2*x_old)
        int c4 = idx >> 2, towner = c4 & (TPB3 - 1), vsel = c4 >> 10, e = idx & 3;
        if (t == towner) {
            f32x4 s4;
            if (vsel == 0) s4 = sg[0]; else if (vsel == 1) s4 = sg[1];
            else if (vsel == 2) s4 = sg[2]; else s4 = sg[3];
            float d = (e == 0) ? s4.x : (e == 1) ? s4.y : (e == 2) ? s4.z : s4.w;
            if (e == 0) s4.x = -s4.x; else if (e == 1) s4.y = -s4.y;
            else if (e == 2) s4.z = -s4.z; else s4.w = -s4.w;
            if (vsel == 0) sg[0] = s4; else if (vsel == 1) sg[1] = s4;
            else if (vsel == 2) sg[2] = s4; else sg[3] = s4;
            s_delta = d;
        }
        __syncthreads();  // bar2: s_delta visible; also protects redf/redi reuse
        float delta = s_delta;
        h[0].x = fmaf(delta, wl0.x, h[0].x); h[0].y = fmaf(delta, wl0.y, h[0].y);
        h[0].z = fmaf(delta, wl0.z, h[0].z); h[0].w = fmaf(delta, wl0.w, h[0].w);
        h[1].x = fmaf(delta, wl1.x, h[1].x); h[1].y = fmaf(delta, wl1.y, h[1].y);
        h[1].z = fmaf(delta, wl1.z, h[1].z); h[1].w = fmaf(delta, wl1.w, h[1].w);
        h[2].x = fmaf(delta, wl2.x, h[2].x); h[2].y = fmaf(delta, wl2.y, h[2].y);
        h[2].z = fmaf(delta, wl2.z, h[2].z); h[2].w = fmaf(delta, wl2.w, h[2].w);
        h[3].x = fmaf(delta, wl3.x, h[3].x); h[3].y = fmaf(delta, wl3.y, h[3].y);
        h[3].z = fmaf(delta, wl3.z, h[3].z); h[3].w = fmaf(delta, wl3.w, h[3].w);
    }

    // Zy
    lmax = -INFINITY;
#pragma unroll
    for (int v = 0; v < 4; ++v) {
        f32x4 l = sg[v] * h[v] * 0.5f;
        lmax = fmaxf(lmax, fmaxf(fmaxf(l.x, l.y), fmaxf(l.z, l.w)));
    }
    m = block_reduce_max(lmax, redf);
    lsum = 0.f;
#pragma unroll
    for (int v = 0; v < 4; ++v) {
        f32x4 l = sg[v] * h[v] * 0.5f;
        lsum += expf(l.x - m) + expf(l.y - m) + expf(l.z - m) + expf(l.w - m);
    }
    S = block_reduce_sum(lsum, redf);
    float Zy = logf(S) + m;

    int accepted = (expf(Zx - Zy) >= au[b]) ? 1 : 0;
    f32x4* ov = (f32x4*)(out + (size_t)b * DIM);
#pragma unroll
    for (int v = 0; v < 4; ++v) {
        f32x4 y;
        y.x = (sg[v].x < 0.f) ? 1.f : 0.f;
        y.y = (sg[v].y < 0.f) ? 1.f : 0.f;
        y.z = (sg[v].z < 0.f) ? 1.f : 0.f;
        y.w = (sg[v].w < 0.f) ? 1.f : 0.f;
        ov[t + v * TPB3] = accepted ? y : xin[t + v * TPB3];
    }
}

extern "C" void kernel_launch(void* const* d_in, const int* in_sizes, int n_in,
                              void* d_out, int out_size, void* d_ws, size_t ws_size,
                              hipStream_t stream) {
    (void)in_sizes; (void)n_in; (void)out_size; (void)ws_size;
    const float* x      = (const float*)d_in[0];
    const float* W      = (const float*)d_in[1];
    const float* bias   = (const float*)d_in[2];
    const float* gumbel = (const float*)d_in[3];
    const float* au     = (const float*)d_in[4];
    const int*   radius = (const int*)d_in[5];
    float* out = (float*)d_out;

    // ws layout: xT (2 MB) | partial (NSLOTS * 2 MB = 64 MB) | h0 (2 MB)
    float* xT = (float*)d_ws;
    size_t xt_elems = (size_t)DIM * BSIZE;
    float* partial = xT + xt_elems;
    float* h0 = partial + (size_t)NSLOTS * BSIZE * DIM;

    k_xpose<<<DIM / 64, 256, 0, stream>>>(x, xT);
    dim3 g1(DIM / (TPB1 * 4), NSLOTS);  // (16, 32) = 512 blocks
    k_matmul<<<g1, TPB1, 0, stream>>>(W, xT, partial);
    k_reduce<<<(BSIZE * DIM / 4) / 256, 256, 0, stream>>>(partial, bias, h0);
    k_sample<<<BSIZE, TPB3, 0, stream>>>(x, W, h0, gumbel, au, radius, out);
}